// Round 5
// baseline (3200.293 us; speedup 1.0000x reference)
//
#include <hip/hip_runtime.h>
#include <hip/hip_bf16.h>

#define T_STEPS 256
#define BATCH   64
#define DIM_I   256
#define DIM_H   256
#define NBR     8
#define F_DIM   1024

typedef __attribute__((ext_vector_type(8))) short short8;
typedef __attribute__((ext_vector_type(4))) float floatx4;

// workspace layout (bytes)
#define WX_OFF  0u                  // 4 MB  bf16 W_x fragments [n][ks8][ct64][lane64][8]
#define WH_OFF  (4u<<20)            // 4 MB  bf16 W_h fragments [n][ks8][ct64][lane64][8]
#define C_OFF   (8u<<20)            // 512 KB fp32 c carry  [n][rt][tid1024][4]
#define H_OFF   ((8u<<20) + 0x80000u) // 256 KB bf16 h carry [n][rt][row16][col256]
#define ZX_OFF  (16u<<20)           // CT * 2 MB fp32 z_x fragments [tt][n][rt][ct][lane][4]

__device__ __forceinline__ float sigmoid_fast(float x) {
    return 1.0f / (1.0f + __expf(-x));
}
__device__ __forceinline__ float tanh_fast(float x) {
    return 1.0f - 2.0f / (__expf(2.0f * x) + 1.0f);
}
// fp32 -> bf16 bits, round-to-nearest-even (finite inputs only)
__device__ __forceinline__ short f2bf(float f) {
    unsigned u = __float_as_uint(f);
    u += 0x7FFFu + ((u >> 16) & 1u);
    return (short)(u >> 16);
}

// ---------------------------------------------------------------------------
// Kernel 1: convert weight fp32 [N][512][1024] -> bf16 B-fragment order,
// split into W_x (k<256) and W_h (k>=256).
// Fragment layout: [n][ks][ct][lane][j], lane = qr*16 + c0, where for global k:
// ks=(k&255)>>5, qr=(k>>3)&3, j=k&7; ct=f>>4, c0=f&15.
// ---------------------------------------------------------------------------
__global__ void __launch_bounds__(256)
prep_kernel(const float* __restrict__ weight, short* __restrict__ wx,
            short* __restrict__ wh) {
    int id = blockIdx.x * 256 + threadIdx.x;     // 8*512*1024 = 4194304 total
    int f  = id & 1023;
    int kk = (id >> 10) & 511;
    int n  = id >> 19;
    float v = weight[(size_t)id];                // [n][kk][f] contiguous == id
    int ks = (kk & 255) >> 5;
    int qr = (kk >> 3) & 3;
    int j  = kk & 7;
    int ct = f >> 4;
    int c0 = f & 15;
    int lane = qr * 16 + c0;
    size_t o = ((((size_t)n * 8 + ks) * 64 + ct) * 64 + lane) * 8 + j;
    (kk < 256 ? wx : wh)[o] = f2bf(v);
}

// ---------------------------------------------------------------------------
// Kernel 2: z_x = x@W_x + bias, fp32 D-fragment order. Grid CT*8 x 256 thr.
// M split into two halves of 32 rows so live regs fit 128 (the allocator
// hard-caps at 128 arch VGPRs; rounds 1-4 showed over-budget kernels spill
// into the loop). W_x re-read once more from L2 per block: cheap.
// ---------------------------------------------------------------------------
__global__ void __launch_bounds__(256)
xgemm_kernel(const float* __restrict__ x, const short* __restrict__ wxg,
             const float* __restrict__ bias_i, const float* __restrict__ bias_h,
             floatx4* __restrict__ zx, int t0) {
    const int tid = threadIdx.x;
    const int lane = tid & 63, w = tid >> 6;
    const int l15 = lane & 15, quad = lane >> 4;
    const int n = blockIdx.x & 7;
    const int tt = blockIdx.x >> 3;
    const int t = t0 + tt;
    const short8* wx8 = (const short8*)wxg + (size_t)n * 8 * 64 * 64;

    for (int mg = 0; mg < 2; ++mg) {           // NOT unrolled: halves reg demand
        short8 a2[2][8];
#pragma unroll
        for (int mm = 0; mm < 2; ++mm) {
            const float* xr = x + ((size_t)t * BATCH + mg * 32 + mm * 16 + l15) * DIM_I + quad * 8;
#pragma unroll
            for (int ks = 0; ks < 8; ++ks) {
                const floatx4* p = (const floatx4*)(xr + ks * 32);
                floatx4 u = p[0], v = p[1];
                short8 af;
                af[0] = f2bf(u[0]); af[1] = f2bf(u[1]); af[2] = f2bf(u[2]); af[3] = f2bf(u[3]);
                af[4] = f2bf(v[0]); af[5] = f2bf(v[1]); af[6] = f2bf(v[2]); af[7] = f2bf(v[3]);
                a2[mm][ks] = af;
            }
        }
        for (int ci = 0; ci < 16; ++ci) {
            const int ct = w * 16 + ci;
            float bb = bias_i[n * F_DIM + ct * 16 + l15] + bias_h[n * F_DIM + ct * 16 + l15];
            short8 bw[8];
#pragma unroll
            for (int ks = 0; ks < 8; ++ks)
                bw[ks] = wx8[(ks * 64 + ct) * 64 + lane];
#pragma unroll
            for (int mm = 0; mm < 2; ++mm) {
                floatx4 acc = (floatx4){bb, bb, bb, bb};
#pragma unroll
                for (int ks = 0; ks < 8; ++ks)
                    acc = __builtin_amdgcn_mfma_f32_16x16x32_bf16(a2[mm][ks], bw[ks], acc, 0, 0, 0);
                zx[((((size_t)tt * 8 + n) * 4 + (mg * 2 + mm)) * 64 + ct) * 64 + lane] = acc;
            }
        }
    }
}

// ---------------------------------------------------------------------------
// Kernel 3: recurrence. 32 blocks (n = bid&7, rt = bid>>3), 1024 threads =
// 16 waves = 4 waves/SIMD (2x the TLP of rounds 1-4). Wave w owns coltiles
// ct = nt*16 + w, nt = gate 0..3 -> h-cols w*16..w*16+15; epilogue lane-local.
//
// HONEST 128-VGPR BUDGET (the allocator hard-caps at 128; everything must
// fit or it spills into the loop -- the root cause of rounds 1-4's 9us/step):
//   acc 16 + wr(ks0,1) 32 + sbA/sbB 32 + a-prefetch 8 + c 4 + dur 8
//   + transients ~25  ~= 125.
// W_h residency: ks0,1 regs; ks3,4 LDS (128 KB); ks2,5,6,7 streamed from L2
// with >=2-row lookahead (next step's S2/S5 issued under this step's
// epilogue -- stream never drains). Inter-step barrier is raw
// `s_waitcnt lgkmcnt(0); s_barrier` so cross-barrier vm prefetches survive
// (__syncthreads drains vmcnt(0)). Accumulation order: zx-first, ks
// ascending == previous rounds -> bit-identical numerics.
// ---------------------------------------------------------------------------
__global__ void __launch_bounds__(1024)
rec_kernel(const floatx4* __restrict__ zx, const int* __restrict__ dur,
           const short* __restrict__ whg, float* __restrict__ out,
           float* __restrict__ c_carry, short* __restrict__ h_carry,
           int t0, int CT) {
    __shared__ short hlds[2][16 * 256];     // 16 KB h ping-pong, XOR-swizzled
    __shared__ short wl[2 * 4 * 16 * 512];  // 128 KB ks3,4: [(ksl*4+nt)*16+w][lane8]

    const int tid = threadIdx.x;
    const int lane = tid & 63, w = tid >> 6;      // 16 waves
    const int l15 = lane & 15, quad = lane >> 4;
    const int n = blockIdx.x & 7;
    const int rt = blockIdx.x >> 3;
    const int r0 = rt * 16;

    const short8* wh8 = (const short8*)whg + (size_t)n * 8 * 64 * 64;
    const int swz = (l15 & 7) << 4;               // A-read swizzle (row = l15)
    char* h0 = (char*)&hlds[0][0];
    char* h1 = (char*)&hlds[1][0];

    // ---- h carry -> hlds[0] (swizzled; zeroed by host at t=0) ----
    if (tid < 512) {
        const short8* src = (const short8*)(h_carry + ((size_t)n * 4 + rt) * 4096);
        int row = tid >> 5, cg = tid & 31;
        *(short8*)(h0 + row * 512 + ((cg * 16) ^ ((row & 7) << 4))) = src[tid];
    }
    // ---- c carry ----
    float c[4];
    {
        const float* cp = c_carry + (((size_t)n * 4 + rt) * 1024 + tid) * 4;
#pragma unroll
        for (int r = 0; r < 4; ++r) c[r] = cp[r];
    }
    // ---- LDS-pinned W ks3,4 ----
#pragma unroll
    for (int ksl = 0; ksl < 2; ++ksl)
#pragma unroll
        for (int nt = 0; nt < 4; ++nt) {
            short8 v = wh8[((ksl + 3) * 64 + nt * 16 + w) * 64 + lane];
            *(short8*)(&wl[(((ksl * 4 + nt) * 16 + w) * 64 + lane) * 8]) = v;
        }
    // ---- reg-pinned W ks0,1 (32 VGPR, honest fit) ----
    short8 wr0[4], wr1[4];
#pragma unroll
    for (int nt = 0; nt < 4; ++nt) {
        wr0[nt] = wh8[(0 * 64 + nt * 16 + w) * 64 + lane];
        wr1[nt] = wh8[(1 * 64 + nt * 16 + w) * 64 + lane];
        asm volatile("" : "+v"(wr0[nt]));
        asm volatile("" : "+v"(wr1[nt]));
    }
    // ---- stream pipeline fill: sbA <- S2, sbB <- S5 ----
    short8 sbA[4], sbB[4];
#pragma unroll
    for (int nt = 0; nt < 4; ++nt) {
        sbA[nt] = wh8[(2 * 64 + nt * 16 + w) * 64 + lane];
        sbB[nt] = wh8[(5 * 64 + nt * 16 + w) * 64 + lane];
    }
    // ---- acc init = z_x(tt=0); dur(t0) ----
    const size_t zxb = (size_t)(n * 4 + rt) * 4096 + lane;
    floatx4 acc[4];
#pragma unroll
    for (int nt = 0; nt < 4; ++nt)
        acc[nt] = zx[zxb + (size_t)(nt * 16 + w) * 64];
    int4 dA = *(const int4*)(dur + (size_t)t0 * BATCH + r0 + quad * 4);
    int4 dB;

    __syncthreads();  // prologue only (vmcnt drain here is harmless, once)

#define LDA(HC, KS) (*(const short8*)((HC) + l15 * 512 + (((KS) * 64 + quad * 16) ^ swz)))
#define MFMA4(AV, B0, B1, B2, B3)                                              \
    acc[0] = __builtin_amdgcn_mfma_f32_16x16x32_bf16((AV), (B0), acc[0], 0, 0, 0); \
    acc[1] = __builtin_amdgcn_mfma_f32_16x16x32_bf16((AV), (B1), acc[1], 0, 0, 0); \
    acc[2] = __builtin_amdgcn_mfma_f32_16x16x32_bf16((AV), (B2), acc[2], 0, 0, 0); \
    acc[3] = __builtin_amdgcn_mfma_f32_16x16x32_bf16((AV), (B3), acc[3], 0, 0, 0);

#define STEP(TT, HC, HN, DC, DN)                                               \
    {                                                                          \
        const int t_ = t0 + (TT);                                              \
        const int ttn_ = ((TT) + 1 < CT) ? (TT) + 1 : (TT);                    \
        short8 aA = LDA(HC, 0);                                                \
        short8 aB = LDA(HC, 1);                                                \
        (DN) = *(const int4*)(dur + (size_t)(t0 + ttn_) * BATCH + r0 + quad * 4); \
        __builtin_amdgcn_s_setprio(1);                                         \
        /* ks0,1: register-resident */                                         \
        MFMA4(aA, wr0[0], wr0[1], wr0[2], wr0[3]);                             \
        aA = LDA(HC, 2);                                                       \
        MFMA4(aB, wr1[0], wr1[1], wr1[2], wr1[3]);                             \
        aB = LDA(HC, 3);                                                       \
        /* ks2: stream (issued prev step) -> refill S6 */                      \
        MFMA4(aA, sbA[0], sbA[1], sbA[2], sbA[3]);                             \
        _Pragma("unroll")                                                      \
        for (int nt = 0; nt < 4; ++nt)                                         \
            sbA[nt] = wh8[(6 * 64 + nt * 16 + w) * 64 + lane];                 \
        aA = LDA(HC, 4);                                                       \
        /* ks3,4: LDS-resident */                                              \
        {                                                                      \
            short8 b0 = *(const short8*)(&wl[(((0 * 4 + 0) * 16 + w) * 64 + lane) * 8]); \
            short8 b1 = *(const short8*)(&wl[(((0 * 4 + 1) * 16 + w) * 64 + lane) * 8]); \
            short8 b2 = *(const short8*)(&wl[(((0 * 4 + 2) * 16 + w) * 64 + lane) * 8]); \
            short8 b3 = *(const short8*)(&wl[(((0 * 4 + 3) * 16 + w) * 64 + lane) * 8]); \
            MFMA4(aB, b0, b1, b2, b3);                                         \
        }                                                                      \
        aB = LDA(HC, 5);                                                       \
        {                                                                      \
            short8 b0 = *(const short8*)(&wl[(((1 * 4 + 0) * 16 + w) * 64 + lane) * 8]); \
            short8 b1 = *(const short8*)(&wl[(((1 * 4 + 1) * 16 + w) * 64 + lane) * 8]); \
            short8 b2 = *(const short8*)(&wl[(((1 * 4 + 2) * 16 + w) * 64 + lane) * 8]); \
            short8 b3 = *(const short8*)(&wl[(((1 * 4 + 3) * 16 + w) * 64 + lane) * 8]); \
            MFMA4(aA, b0, b1, b2, b3);                                         \
        }                                                                      \
        aA = LDA(HC, 6);                                                       \
        /* ks5: stream -> refill S7 */                                         \
        MFMA4(aB, sbB[0], sbB[1], sbB[2], sbB[3]);                             \
        _Pragma("unroll")                                                      \
        for (int nt = 0; nt < 4; ++nt)                                         \
            sbB[nt] = wh8[(7 * 64 + nt * 16 + w) * 64 + lane];                 \
        aB = LDA(HC, 7);                                                       \
        /* ks6 (S6, issued at ks2) -> refill next-step S2 */                   \
        MFMA4(aA, sbA[0], sbA[1], sbA[2], sbA[3]);                             \
        _Pragma("unroll")                                                      \
        for (int nt = 0; nt < 4; ++nt)                                         \
            sbA[nt] = wh8[(2 * 64 + nt * 16 + w) * 64 + lane];                 \
        /* ks7 (S7, issued at ks5) */                                          \
        MFMA4(aB, sbB[0], sbB[1], sbB[2], sbB[3]);                             \
        __builtin_amdgcn_s_setprio(0);                                         \
        /* pointwise LSTM epilogue: lane-local, 4 cells */                     \
        const int dv_[4] = {(DC).x, (DC).y, (DC).z, (DC).w};                   \
        _Pragma("unroll")                                                      \
        for (int r = 0; r < 4; ++r) {                                          \
            const bool freeze = n > (dv_[r] >> 3);                             \
            const int row = quad * 4 + r;                                      \
            float zi = acc[0][r], zf = acc[1][r], zo = acc[2][r], zg = acc[3][r]; \
            float ig = sigmoid_fast(zi), fg = sigmoid_fast(zf);                \
            float og = sigmoid_fast(zo), gg = tanh_fast(zg);                   \
            float cn = freeze ? c[r] : fg * c[r] + ig * gg;                    \
            c[r] = cn;                                                         \
            float hv = og * tanh_fast(cn);                                     \
            const int hcol = w * 16 + l15;                                     \
            out[(((size_t)t_ * NBR + n) * BATCH + (r0 + row)) * DIM_H + hcol] = hv; \
            *(short*)((HN) + row * 512 + ((2 * hcol) ^ ((row & 7) << 4))) = f2bf(hv); \
        }                                                                      \
        /* next-step S5 + zx under the epilogue/barrier shadow */              \
        _Pragma("unroll")                                                      \
        for (int nt = 0; nt < 4; ++nt)                                         \
            sbB[nt] = wh8[(5 * 64 + nt * 16 + w) * 64 + lane];                 \
        _Pragma("unroll")                                                      \
        for (int nt = 0; nt < 4; ++nt)                                         \
            acc[nt] = zx[(size_t)ttn_ * 131072 + zxb + (size_t)(nt * 16 + w) * 64]; \
    }

    for (int tt = 0; tt < CT; tt += 2) {
        STEP(tt, h0, h1, dA, dB);
        asm volatile("s_waitcnt lgkmcnt(0)\n\ts_barrier" ::: "memory");
        STEP(tt + 1, h1, h0, dB, dA);
        asm volatile("s_waitcnt lgkmcnt(0)\n\ts_barrier" ::: "memory");
    }
#undef STEP
#undef MFMA4
#undef LDA

    // ---- store carries for next chunk (CT even -> final h is in hlds[0]) ----
    {
        float* cp = c_carry + (((size_t)n * 4 + rt) * 1024 + tid) * 4;
#pragma unroll
        for (int r = 0; r < 4; ++r) cp[r] = c[r];
        if (tid < 512) {
            int row = tid >> 5, cg = tid & 31;
            short8 v = *(const short8*)(h0 + row * 512 + ((cg * 16) ^ ((row & 7) << 4)));
            ((short8*)(h_carry + ((size_t)n * 4 + rt) * 4096))[tid] = v;
        }
    }
}

extern "C" void kernel_launch(void* const* d_in, const int* in_sizes, int n_in,
                              void* d_out, int out_size, void* d_ws, size_t ws_size,
                              hipStream_t stream) {
    const float* x      = (const float*)d_in[0];
    const int*   durp   = (const int*)d_in[1];
    const float* weight = (const float*)d_in[2];
    const float* bias_i = (const float*)d_in[3];
    const float* bias_h = (const float*)d_in[4];
    float* out = (float*)d_out;
    char*  ws  = (char*)d_ws;

    short*   wx      = (short*)(ws + WX_OFF);
    short*   wh      = (short*)(ws + WH_OFF);
    float*   c_carry = (float*)(ws + C_OFF);
    short*   h_carry = (short*)(ws + H_OFF);
    floatx4* zxp     = (floatx4*)(ws + ZX_OFF);

    // pick largest T-chunk whose z_x buffer fits the workspace (2 MB / step)
    int CT = 256;
    while (CT > 2 && (size_t)ZX_OFF + (size_t)CT * 2097152ull > ws_size) CT >>= 1;

    // zero h/c carries (t=0 state)
    hipMemsetAsync(ws + C_OFF, 0, 524288 + 262144, stream);

    // weight repack: fp32 -> bf16 fragments
    prep_kernel<<<16384, 256, 0, stream>>>(weight, wx, wh);

    for (int t0 = 0; t0 < T_STEPS; t0 += CT) {
        xgemm_kernel<<<CT * 8, 256, 0, stream>>>(x, wx, bias_i, bias_h, zxp, t0);
        rec_kernel<<<32, 1024, 0, stream>>>(zxp, durp, wh, out, c_carry, h_carry, t0, CT);
    }
}

// Round 6
// 3002.738 us; speedup vs baseline: 1.0658x; 1.0658x over previous
//
#include <hip/hip_runtime.h>
#include <hip/hip_bf16.h>

#define T_STEPS 256
#define BATCH   64
#define DIM_I   256
#define DIM_H   256
#define NBR     8
#define F_DIM   1024

typedef __attribute__((ext_vector_type(8))) short short8;
typedef __attribute__((ext_vector_type(4))) float floatx4;

// workspace layout (bytes)
#define WX_OFF  0u                  // 4 MB  bf16 W_x fragments [n][ks8][ct64][lane64][8]
#define WH_OFF  (4u<<20)            // 4 MB  bf16 W_h fragments [n][ks8][ct64][lane64][8]
#define C_OFF   (8u<<20)            // 512 KB fp32 c carry  [n][rt][tid1024][4]
#define H_OFF   ((8u<<20) + 0x80000u) // 256 KB bf16 h carry [n][rt][row16][col256]
#define ZX_OFF  (16u<<20)           // CT * 2 MB fp32 z_x fragments [tt][n][rt][ct][lane][4]

__device__ __forceinline__ float sigmoid_fast(float x) {
    return 1.0f / (1.0f + __expf(-x));
}
__device__ __forceinline__ float tanh_fast(float x) {
    return 1.0f - 2.0f / (__expf(2.0f * x) + 1.0f);
}
// fp32 -> bf16 bits, round-to-nearest-even (finite inputs only)
__device__ __forceinline__ short f2bf(float f) {
    unsigned u = __float_as_uint(f);
    u += 0x7FFFu + ((u >> 16) & 1u);
    return (short)(u >> 16);
}

// ---------------------------------------------------------------------------
// Kernel 1: convert weight fp32 [N][512][1024] -> bf16 B-fragment order,
// split into W_x (k<256) and W_h (k>=256).
// ---------------------------------------------------------------------------
__global__ void __launch_bounds__(256)
prep_kernel(const float* __restrict__ weight, short* __restrict__ wx,
            short* __restrict__ wh) {
    int id = blockIdx.x * 256 + threadIdx.x;     // 8*512*1024 = 4194304 total
    int f  = id & 1023;
    int kk = (id >> 10) & 511;
    int n  = id >> 19;
    float v = weight[(size_t)id];                // [n][kk][f] contiguous == id
    int ks = (kk & 255) >> 5;
    int qr = (kk >> 3) & 3;
    int j  = kk & 7;
    int ct = f >> 4;
    int c0 = f & 15;
    int lane = qr * 16 + c0;
    size_t o = ((((size_t)n * 8 + ks) * 64 + ct) * 64 + lane) * 8 + j;
    (kk < 256 ? wx : wh)[o] = f2bf(v);
}

// ---------------------------------------------------------------------------
// Kernel 2: z_x = x@W_x + bias, fp32 D-fragment order. Grid CT*8 x 256 thr.
// M processed in two halves of 32 rows so live regs fit the 128 budget.
// ---------------------------------------------------------------------------
__global__ void __launch_bounds__(256)
xgemm_kernel(const float* __restrict__ x, const short* __restrict__ wxg,
             const float* __restrict__ bias_i, const float* __restrict__ bias_h,
             floatx4* __restrict__ zx, int t0) {
    const int tid = threadIdx.x;
    const int lane = tid & 63, w = tid >> 6;
    const int l15 = lane & 15, quad = lane >> 4;
    const int n = blockIdx.x & 7;
    const int tt = blockIdx.x >> 3;
    const int t = t0 + tt;
    const short8* wx8 = (const short8*)wxg + (size_t)n * 8 * 64 * 64;

    for (int mg = 0; mg < 2; ++mg) {           // NOT unrolled: halves reg demand
        short8 a2[2][8];
#pragma unroll
        for (int mm = 0; mm < 2; ++mm) {
            const float* xr = x + ((size_t)t * BATCH + mg * 32 + mm * 16 + l15) * DIM_I + quad * 8;
#pragma unroll
            for (int ks = 0; ks < 8; ++ks) {
                const floatx4* p = (const floatx4*)(xr + ks * 32);
                floatx4 u = p[0], v = p[1];
                short8 af;
                af[0] = f2bf(u[0]); af[1] = f2bf(u[1]); af[2] = f2bf(u[2]); af[3] = f2bf(u[3]);
                af[4] = f2bf(v[0]); af[5] = f2bf(v[1]); af[6] = f2bf(v[2]); af[7] = f2bf(v[3]);
                a2[mm][ks] = af;
            }
        }
        for (int ci = 0; ci < 16; ++ci) {
            const int ct = w * 16 + ci;
            float bb = bias_i[n * F_DIM + ct * 16 + l15] + bias_h[n * F_DIM + ct * 16 + l15];
            short8 bw[8];
#pragma unroll
            for (int ks = 0; ks < 8; ++ks)
                bw[ks] = wx8[(ks * 64 + ct) * 64 + lane];
#pragma unroll
            for (int mm = 0; mm < 2; ++mm) {
                floatx4 acc = (floatx4){bb, bb, bb, bb};
#pragma unroll
                for (int ks = 0; ks < 8; ++ks)
                    acc = __builtin_amdgcn_mfma_f32_16x16x32_bf16(a2[mm][ks], bw[ks], acc, 0, 0, 0);
                zx[((((size_t)tt * 8 + n) * 4 + (mg * 2 + mm)) * 64 + ct) * 64 + lane] = acc;
            }
        }
    }
}

// ---------------------------------------------------------------------------
// Kernel 3: recurrence. 32 blocks (n = bid&7, rt = bid>>3), 1024 threads =
// 16 waves = 4 waves/SIMD. Wave w owns coltiles ct = nt*16 + w (gate nt=0..3)
// -> h-cols w*16..w*16+15; LSTM epilogue is lane-local.
//
// ROUND-6 KEY CHANGE: amdgpu_waves_per_eu(4,4) pins the allocator's
// occupancy target to exactly 4 waves/EU -> register budget 512/4 = 128,
// matching this kernel's ~121-reg live set. Round 5 proved the allocator
// (not the code) picks the budget: bare launch_bounds(1024) targeted
// 8 waves/EU -> 64 regs -> ~60 regs spilled INTO the t-loop (the 11 us/step).
//   budget: acc 16 + wr 32 + sbA/sbB 32 + aA/aB 8 + c 4 + dv4 4 + temps ~25.
// W_h residency: ks0,1 regs; ks3,4 LDS (128 KB); ks2,5,6,7 streamed from L2,
// refills placed >=300 cyc before use (S6 after ks2, S7 after ks5,
// next-step S2 after ks6, next-step S5 + zx under the epilogue shadow).
// Inter-step barrier is raw `s_waitcnt lgkmcnt(0); s_barrier` so in-flight
// vm prefetches survive the barrier. Accumulation: zx-first, ks-ascending
// == previous rounds -> bit-identical numerics.
// ---------------------------------------------------------------------------
__global__ void __attribute__((amdgpu_flat_work_group_size(1024, 1024),
                               amdgpu_waves_per_eu(4, 4)))
rec_kernel(const floatx4* __restrict__ zx, const int* __restrict__ dur,
           const short* __restrict__ whg, float* __restrict__ out,
           float* __restrict__ c_carry, short* __restrict__ h_carry,
           int t0, int CT) {
    __shared__ short hlds[2][16 * 256];     // 16 KB h ping-pong, XOR-swizzled
    __shared__ short wl[2 * 4 * 16 * 512];  // 128 KB ks3,4: [(ksl*4+nt)*16+w][lane8]

    const int tid = threadIdx.x;
    const int lane = tid & 63, w = tid >> 6;      // 16 waves
    const int l15 = lane & 15, quad = lane >> 4;
    const int n = blockIdx.x & 7;
    const int rt = blockIdx.x >> 3;
    const int r0 = rt * 16;

    const short8* wh8 = (const short8*)whg + (size_t)n * 8 * 64 * 64;
    const int swz = (l15 & 7) << 4;               // A-read swizzle (row = l15)
    char* h0 = (char*)&hlds[0][0];
    char* h1 = (char*)&hlds[1][0];

    // ---- h carry -> hlds[0] (swizzled; zeroed by host at t=0) ----
    if (tid < 512) {
        const short8* src = (const short8*)(h_carry + ((size_t)n * 4 + rt) * 4096);
        int row = tid >> 5, cg = tid & 31;
        *(short8*)(h0 + row * 512 + ((cg * 16) ^ ((row & 7) << 4))) = src[tid];
    }
    // ---- c carry ----
    float c[4];
    {
        const float* cp = c_carry + (((size_t)n * 4 + rt) * 1024 + tid) * 4;
#pragma unroll
        for (int r = 0; r < 4; ++r) c[r] = cp[r];
    }
    // ---- LDS-pinned W ks3,4 ----
#pragma unroll
    for (int ksl = 0; ksl < 2; ++ksl)
#pragma unroll
        for (int nt = 0; nt < 4; ++nt) {
            short8 v = wh8[((ksl + 3) * 64 + nt * 16 + w) * 64 + lane];
            *(short8*)(&wl[(((ksl * 4 + nt) * 16 + w) * 64 + lane) * 8]) = v;
        }
    // ---- reg-pinned W ks0,1 (32 VGPR, honest fit) ----
    short8 wr0[4], wr1[4];
#pragma unroll
    for (int nt = 0; nt < 4; ++nt) {
        wr0[nt] = wh8[(0 * 64 + nt * 16 + w) * 64 + lane];
        wr1[nt] = wh8[(1 * 64 + nt * 16 + w) * 64 + lane];
        asm volatile("" : "+v"(wr0[nt]));
        asm volatile("" : "+v"(wr1[nt]));
    }
    // ---- stream pipeline fill: sbA <- S2, sbB <- S5 ----
    short8 sbA[4], sbB[4];
#pragma unroll
    for (int nt = 0; nt < 4; ++nt) {
        sbA[nt] = wh8[(2 * 64 + nt * 16 + w) * 64 + lane];
        sbB[nt] = wh8[(5 * 64 + nt * 16 + w) * 64 + lane];
    }
    // ---- acc init = z_x(tt=0) ----
    const size_t zxb = (size_t)(n * 4 + rt) * 4096 + lane;
    floatx4 acc[4];
#pragma unroll
    for (int nt = 0; nt < 4; ++nt)
        acc[nt] = zx[zxb + (size_t)(nt * 16 + w) * 64];

    __syncthreads();  // prologue only (vmcnt drain here is harmless, once)

#define LDA(HC, KS) (*(const short8*)((HC) + l15 * 512 + (((KS) * 64 + quad * 16) ^ swz)))
#define MFMA4(AV, B0, B1, B2, B3)                                              \
    acc[0] = __builtin_amdgcn_mfma_f32_16x16x32_bf16((AV), (B0), acc[0], 0, 0, 0); \
    acc[1] = __builtin_amdgcn_mfma_f32_16x16x32_bf16((AV), (B1), acc[1], 0, 0, 0); \
    acc[2] = __builtin_amdgcn_mfma_f32_16x16x32_bf16((AV), (B2), acc[2], 0, 0, 0); \
    acc[3] = __builtin_amdgcn_mfma_f32_16x16x32_bf16((AV), (B3), acc[3], 0, 0, 0);

#define STEP(TT, HC, HN)                                                       \
    {                                                                          \
        const int t_ = t0 + (TT);                                              \
        const int ttn_ = ((TT) + 1 < CT) ? (TT) + 1 : (TT);                    \
        /* dur for THIS step: full MFMA chain as latency cover */              \
        const int4 dv4 = *(const int4*)(dur + (size_t)t_ * BATCH + r0 + quad * 4); \
        short8 aA = LDA(HC, 0);                                                \
        short8 aB = LDA(HC, 1);                                                \
        __builtin_amdgcn_s_setprio(1);                                         \
        /* ks0,1: register-resident */                                         \
        MFMA4(aA, wr0[0], wr0[1], wr0[2], wr0[3]);                             \
        aA = LDA(HC, 2);                                                       \
        MFMA4(aB, wr1[0], wr1[1], wr1[2], wr1[3]);                             \
        aB = LDA(HC, 3);                                                       \
        /* ks2: stream (issued prev step) -> refill S6 */                      \
        MFMA4(aA, sbA[0], sbA[1], sbA[2], sbA[3]);                             \
        _Pragma("unroll")                                                      \
        for (int nt = 0; nt < 4; ++nt)                                         \
            sbA[nt] = wh8[(6 * 64 + nt * 16 + w) * 64 + lane];                 \
        aA = LDA(HC, 4);                                                       \
        /* ks3,4: LDS-resident */                                              \
        {                                                                      \
            short8 b0 = *(const short8*)(&wl[(((0 * 4 + 0) * 16 + w) * 64 + lane) * 8]); \
            short8 b1 = *(const short8*)(&wl[(((0 * 4 + 1) * 16 + w) * 64 + lane) * 8]); \
            short8 b2 = *(const short8*)(&wl[(((0 * 4 + 2) * 16 + w) * 64 + lane) * 8]); \
            short8 b3 = *(const short8*)(&wl[(((0 * 4 + 3) * 16 + w) * 64 + lane) * 8]); \
            MFMA4(aB, b0, b1, b2, b3);                                         \
        }                                                                      \
        aB = LDA(HC, 5);                                                       \
        {                                                                      \
            short8 b0 = *(const short8*)(&wl[(((1 * 4 + 0) * 16 + w) * 64 + lane) * 8]); \
            short8 b1 = *(const short8*)(&wl[(((1 * 4 + 1) * 16 + w) * 64 + lane) * 8]); \
            short8 b2 = *(const short8*)(&wl[(((1 * 4 + 2) * 16 + w) * 64 + lane) * 8]); \
            short8 b3 = *(const short8*)(&wl[(((1 * 4 + 3) * 16 + w) * 64 + lane) * 8]); \
            MFMA4(aA, b0, b1, b2, b3);                                         \
        }                                                                      \
        aA = LDA(HC, 6);                                                       \
        /* ks5: stream -> refill S7 */                                         \
        MFMA4(aB, sbB[0], sbB[1], sbB[2], sbB[3]);                             \
        _Pragma("unroll")                                                      \
        for (int nt = 0; nt < 4; ++nt)                                         \
            sbB[nt] = wh8[(7 * 64 + nt * 16 + w) * 64 + lane];                 \
        aB = LDA(HC, 7);                                                       \
        /* ks6 (S6, issued at ks2) -> refill next-step S2 */                   \
        MFMA4(aA, sbA[0], sbA[1], sbA[2], sbA[3]);                             \
        _Pragma("unroll")                                                      \
        for (int nt = 0; nt < 4; ++nt)                                         \
            sbA[nt] = wh8[(2 * 64 + nt * 16 + w) * 64 + lane];                 \
        /* ks7 (S7, issued at ks5) */                                          \
        MFMA4(aB, sbB[0], sbB[1], sbB[2], sbB[3]);                             \
        __builtin_amdgcn_s_setprio(0);                                         \
        /* pointwise LSTM epilogue: lane-local, 4 cells */                     \
        const int dv_[4] = {dv4.x, dv4.y, dv4.z, dv4.w};                       \
        _Pragma("unroll")                                                      \
        for (int r = 0; r < 4; ++r) {                                          \
            const bool freeze = n > (dv_[r] >> 3);                             \
            const int row = quad * 4 + r;                                      \
            float zi = acc[0][r], zf = acc[1][r], zo = acc[2][r], zg = acc[3][r]; \
            float ig = sigmoid_fast(zi), fg = sigmoid_fast(zf);                \
            float og = sigmoid_fast(zo), gg = tanh_fast(zg);                   \
            float cn = freeze ? c[r] : fg * c[r] + ig * gg;                    \
            c[r] = cn;                                                         \
            float hv = og * tanh_fast(cn);                                     \
            const int hcol = w * 16 + l15;                                     \
            out[(((size_t)t_ * NBR + n) * BATCH + (r0 + row)) * DIM_H + hcol] = hv; \
            *(short*)((HN) + row * 512 + ((2 * hcol) ^ ((row & 7) << 4))) = f2bf(hv); \
        }                                                                      \
        /* next-step S5 + zx under the epilogue/barrier shadow */              \
        _Pragma("unroll")                                                      \
        for (int nt = 0; nt < 4; ++nt)                                         \
            sbB[nt] = wh8[(5 * 64 + nt * 16 + w) * 64 + lane];                 \
        _Pragma("unroll")                                                      \
        for (int nt = 0; nt < 4; ++nt)                                         \
            acc[nt] = zx[(size_t)ttn_ * 131072 + zxb + (size_t)(nt * 16 + w) * 64]; \
    }

    for (int tt = 0; tt < CT; tt += 2) {
        STEP(tt, h0, h1);
        asm volatile("s_waitcnt lgkmcnt(0)\n\ts_barrier" ::: "memory");
        STEP(tt + 1, h1, h0);
        asm volatile("s_waitcnt lgkmcnt(0)\n\ts_barrier" ::: "memory");
    }
#undef STEP
#undef MFMA4
#undef LDA

    // ---- store carries for next chunk (CT even -> final h is in hlds[0]) ----
    {
        float* cp = c_carry + (((size_t)n * 4 + rt) * 1024 + tid) * 4;
#pragma unroll
        for (int r = 0; r < 4; ++r) cp[r] = c[r];
        if (tid < 512) {
            int row = tid >> 5, cg = tid & 31;
            short8 v = *(const short8*)(h0 + row * 512 + ((cg * 16) ^ ((row & 7) << 4)));
            ((short8*)(h_carry + ((size_t)n * 4 + rt) * 4096))[tid] = v;
        }
    }
}

extern "C" void kernel_launch(void* const* d_in, const int* in_sizes, int n_in,
                              void* d_out, int out_size, void* d_ws, size_t ws_size,
                              hipStream_t stream) {
    const float* x      = (const float*)d_in[0];
    const int*   durp   = (const int*)d_in[1];
    const float* weight = (const float*)d_in[2];
    const float* bias_i = (const float*)d_in[3];
    const float* bias_h = (const float*)d_in[4];
    float* out = (float*)d_out;
    char*  ws  = (char*)d_ws;

    short*   wx      = (short*)(ws + WX_OFF);
    short*   wh      = (short*)(ws + WH_OFF);
    float*   c_carry = (float*)(ws + C_OFF);
    short*   h_carry = (short*)(ws + H_OFF);
    floatx4* zxp     = (floatx4*)(ws + ZX_OFF);

    // pick largest T-chunk whose z_x buffer fits the workspace (2 MB / step)
    int CT = 256;
    while (CT > 2 && (size_t)ZX_OFF + (size_t)CT * 2097152ull > ws_size) CT >>= 1;

    // zero h/c carries (t=0 state)
    hipMemsetAsync(ws + C_OFF, 0, 524288 + 262144, stream);

    // weight repack: fp32 -> bf16 fragments
    prep_kernel<<<16384, 256, 0, stream>>>(weight, wx, wh);

    for (int t0 = 0; t0 < T_STEPS; t0 += CT) {
        xgemm_kernel<<<CT * 8, 256, 0, stream>>>(x, wx, bias_i, bias_h, zxp, t0);
        rec_kernel<<<32, 1024, 0, stream>>>(zxp, durp, wh, out, c_carry, h_carry, t0, CT);
    }
}